// Round 9
// baseline (286.338 us; speedup 1.0000x reference)
//
#include <hip/hip_runtime.h>
#include <cmath>

typedef _Float16 half_t;
typedef _Float16 half8 __attribute__((ext_vector_type(8)));
typedef _Float16 half4v __attribute__((ext_vector_type(4)));
typedef float float4v __attribute__((ext_vector_type(4)));

#define LOG2E 1.44269504088896340736f

#define GLDS16(g, l)                                                                   \
    __builtin_amdgcn_global_load_lds((const __attribute__((address_space(1))) void*)(g), \
                                     (__attribute__((address_space(3))) void*)(l), 16, 0, 0)

// raw barriers: no compiler-inserted vmcnt(0) drain (the __syncthreads trap)
#define BAR_LGKM() __asm__ volatile("s_waitcnt lgkmcnt(0)\n\ts_barrier" ::: "memory")
#define BAR_VM(n)  __asm__ volatile("s_waitcnt vmcnt(" #n ")\n\ts_barrier" ::: "memory")

// ---------------- cast fp32 -> fp16 ----------------
__global__ void cast_f32_f16(const float* __restrict__ in, half_t* __restrict__ out, int n) {
    int i = (blockIdx.x * blockDim.x + threadIdx.x) * 4;
    if (i >= n) return;
    float4 v = *(const float4*)(in + i);
    half4v o;
    o[0] = (half_t)v.x; o[1] = (half_t)v.y; o[2] = (half_t)v.z; o[3] = (half_t)v.w;
    *(half4v*)(out + i) = o;
}

// ---------------- transpose + cast: in fp32 [R][C] -> out fp16 [C][R] ----------------
__global__ void transpose_cast(const float* __restrict__ in, half_t* __restrict__ out, int R, int C) {
    __shared__ float tile[32][33];
    int c0 = blockIdx.x * 32, r0 = blockIdx.y * 32;
    int tx = threadIdx.x, ty = threadIdx.y; // block (32,8)
    for (int p = 0; p < 4; p++) {
        int r = r0 + ty + p * 8;
        tile[ty + p * 8][tx] = in[(size_t)r * C + c0 + tx];
    }
    __syncthreads();
    for (int p = 0; p < 4; p++) {
        int c = c0 + ty + p * 8;
        out[(size_t)c * R + r0 + tx] = (half_t)tile[tx][ty + p * 8];
    }
}

// ---------------- GEMM: C[M][N] = A[M][K] * Bt[N][K]^T + bias ----------------
// 128x128 tile, BK=32, 4 waves; TRIPLE-buffered global_load_lds (prefetch
// distance 2, vmcnt(8) mid-loop) with raw barriers. LDS rows [128][32halves]
// bank-swizzled: chunk stored at pos (chunk + row/2) & 3 -> 2-way max (free).
// MODE 0: fp32 out + bias. MODE 1: QKV epilogue — RMSNorm per head (Q pre-scaled
// by LOG2E) -> Qh/Kh head-major; V stored transposed into Vt[bh][d][s].
template <int MODE>
__global__ __launch_bounds__(256) void gemm_f16(
    const half_t* __restrict__ A,   // [M][K]
    const half_t* __restrict__ Bt,  // [N][K]
    const float* __restrict__ bias, // [N]
    void* __restrict__ Cout,
    int M, int N, int K,
    const float* __restrict__ wq, const float* __restrict__ wk,
    half_t* __restrict__ Qh, half_t* __restrict__ Kh)
{
    __shared__ __align__(16) half_t As[3][128 * 32];
    __shared__ __align__(16) half_t Bs[3][128 * 32];
    int t = threadIdx.x;
    int lane = t & 63, w = t >> 6;
    int m0 = blockIdx.x * 128, n0 = blockIdx.y * 128;
    int wm = (w >> 1) * 64, wn = (w & 1) * 64;
    int lrow = lane & 15, quad = lane >> 4;

    // staging: thread t covers row t>>2, stored pos t&3 -> loads logical chunk lc
    int lc = ((t & 3) - (t >> 3)) & 3;
    const half_t* gA = A  + (size_t)(m0 + (t >> 2)) * K + lc * 8;
    const half_t* gB = Bt + (size_t)(n0 + (t >> 2)) * K + lc * 8;
    half_t* ldsA[3] = { &As[0][w * 512], &As[1][w * 512], &As[2][w * 512] };
    half_t* ldsB[3] = { &Bs[0][w * 512], &Bs[1][w * 512], &Bs[2][w * 512] };

    // fragment reads: logical chunk = quad, stored pos uniform across frags
    int posq = (quad + (lrow >> 1)) & 3;

    float4v acc[4][4] = {};

    // preload tiles 0,1 -> buf 0,1
    GLDS16(gA,                       ldsA[0]);
    GLDS16(gA + (size_t)64 * K,      ldsA[0] + 2048);
    GLDS16(gB,                       ldsB[0]);
    GLDS16(gB + (size_t)64 * K,      ldsB[0] + 2048);
    GLDS16(gA + 32,                  ldsA[1]);
    GLDS16(gA + (size_t)64 * K + 32, ldsA[1] + 2048);
    GLDS16(gB + 32,                  ldsB[1]);
    GLDS16(gB + (size_t)64 * K + 32, ldsB[1] + 2048);

    int nk = K >> 5;
    for (int ki = 0; ki < nk; ki++) {
        int cur = ki % 3, pre = (ki + 2) % 3;
        BAR_LGKM();                         // readers of buf pre (iter ki-1) done
        if (ki + 2 < nk) {
            int kp = (ki + 2) << 5;
            GLDS16(gA + kp,                  ldsA[pre]);
            GLDS16(gA + (size_t)64 * K + kp, ldsA[pre] + 2048);
            GLDS16(gB + kp,                  ldsB[pre]);
            GLDS16(gB + (size_t)64 * K + kp, ldsB[pre] + 2048);
            BAR_VM(8);                      // cur landed; ki+1, ki+2 in flight
        } else if (ki + 1 < nk) {
            BAR_VM(4);
        } else {
            BAR_VM(0);
        }
        half8 af[4], bf[4];
        for (int i = 0; i < 4; i++) af[i] = *(const half8*)(&As[cur][(wm + i * 16 + lrow) * 32 + posq * 8]);
        for (int i = 0; i < 4; i++) bf[i] = *(const half8*)(&Bs[cur][(wn + i * 16 + lrow) * 32 + posq * 8]);
        for (int mi = 0; mi < 4; mi++)
            for (int ni = 0; ni < 4; ni++)
                acc[mi][ni] = __builtin_amdgcn_mfma_f32_16x16x32_f16(af[mi], bf[ni], acc[mi][ni], 0, 0, 0);
    }

    if (MODE == 0) {
        float* out = (float*)Cout;
        for (int mi = 0; mi < 4; mi++)
            for (int ni = 0; ni < 4; ni++)
                for (int r = 0; r < 4; r++) {
                    int gr = m0 + wm + mi * 16 + quad * 4 + r;
                    int gc = n0 + wn + ni * 16 + lrow;
                    out[(size_t)gr * N + gc] = acc[mi][ni][r] + bias[gc];
                }
    } else {
        int nglob = n0 + wn;            // 64-aligned; one head per wave
        if (nglob < 2048) {
            int isK = nglob >> 10;
            int h = (nglob >> 6) & 15;
            const float* wv = isK ? wk : wq;
            half_t* dst = isK ? Kh : Qh;
            float post = isK ? 1.0f : LOG2E;   // pre-scale Q so attn works in log2 domain
            for (int mi = 0; mi < 4; mi++)
                for (int r = 0; r < 4; r++) {
                    int gr = m0 + wm + mi * 16 + quad * 4 + r;
                    float v[4]; float ss = 0.f;
                    for (int ni = 0; ni < 4; ni++) {
                        v[ni] = acc[mi][ni][r] + bias[nglob + ni * 16 + lrow];
                        ss += v[ni] * v[ni];
                    }
                    ss += __shfl_xor(ss, 1);
                    ss += __shfl_xor(ss, 2);
                    ss += __shfl_xor(ss, 4);
                    ss += __shfl_xor(ss, 8);
                    float rr = rsqrtf(ss * (1.0f / 64.0f) + 1e-6f) * post;
                    int bb = gr >> 11, s = gr & 2047;
                    size_t rowbase = ((size_t)((bb * 16 + h) * 2048 + s)) * 64;
                    for (int ni = 0; ni < 4; ni++) {
                        int d = ni * 16 + lrow;
                        dst[rowbase + d] = (half_t)(v[ni] * rr * wv[d]);
                    }
                }
        } else {
            // V part: store transposed into Vt[bh][d][s] (4 consecutive s per lane)
            half_t* Vt = (half_t*)Cout;
            for (int mi = 0; mi < 4; mi++) {
                int gr = m0 + wm + mi * 16 + quad * 4;   // s-base, 4-aligned
                int bb = gr >> 11, s = gr & 2047;
                for (int ni = 0; ni < 4; ni++) {
                    int dg = nglob + ni * 16 + lrow - 2048;   // 0..1023
                    float bv = bias[nglob + ni * 16 + lrow];
                    half4v oh;
                    for (int r = 0; r < 4; r++) oh[r] = (half_t)(acc[mi][ni][r] + bv);
                    *(half4v*)(Vt + ((size_t)((bb * 16 + (dg >> 6)) * 64 + (dg & 63))) * 2048 + s) = oh;
                }
            }
        }
    }
}

// ---------------- Flash attention, causal, no scale (Q pre-scaled by LOG2E) --
// 8 waves / 128 q-rows, paired q-tiles (i,15-i), XOR-swizzled LDS,
// grid (bh, pair) for XCD L2 sharing, dbuf K/V with RAW barriers (vmcnt(2)).
__global__ __launch_bounds__(512, 4) void attn(
    const half_t* __restrict__ Qh, const half_t* __restrict__ Kh, const half_t* __restrict__ Vt,
    half_t* __restrict__ Z)
{
    __shared__ __align__(16) half_t Ks[2][64 * 64];   // [buf][key][d], chunk-swizzled
    __shared__ __align__(16) half_t Vs[2][64 * 64];   // [buf][d][key], chunk-swizzled
    __shared__ __align__(16) half_t Ps[8 * 16 * 64];  // per-wave [q][key], chunk-swizzled

    int bh = blockIdx.x;
    int b = bh >> 4, h = bh & 15;
    int t = threadIdx.x, lane = t & 63, w = t >> 6;
    int lrow = lane & 15, quad = lane >> 4;

    int sr = w * 8 + (lane >> 3);
    int scc = (lane & 7) ^ ((lane >> 3) & 7);
    const half_t* gK0 = Kh + ((size_t)bh * 2048 + sr) * 64 + scc * 8;
    const half_t* gV0 = Vt + ((size_t)bh * 64 + sr) * 2048 + scc * 8;

    int sw = lrow & 7;
    int cA = (quad ^ sw) * 8;
    int cB = ((quad + 4) ^ sw) * 8;
    half_t* PsW = Ps + w * 1024 + lrow * 64;

    for (int pass = 0; pass < 2; pass++) {
        int qt = pass ? (15 - (int)blockIdx.y) : (int)blockIdx.y;
        int q0w = qt * 128 + w * 16;

        const half_t* Qbase = Qh + ((size_t)bh * 2048 + q0w + lrow) * 64;
        half8 qf0 = *(const half8*)(Qbase + quad * 8);
        half8 qf1 = *(const half8*)(Qbase + 32 + quad * 8);

        float4v ot[4] = {};
        float m = -__builtin_inff(), l = 0.f;

        int nt = 2 * qt + 2;
        __syncthreads();                      // full drain at pass boundary
        GLDS16(gK0, &Ks[0][w * 512]);
        GLDS16(gV0, &Vs[0][w * 512]);

        for (int kt = 0; kt < nt; kt++) {
            int cur = kt & 1, nxt = cur ^ 1;
            int kb = kt * 64;
            BAR_LGKM();                       // prev readers of buf nxt done
            if (kt + 1 < nt) {
                GLDS16(gK0 + (size_t)(kb + 64) * 64, &Ks[nxt][w * 512]);
                GLDS16(gV0 + kb + 64,                &Vs[nxt][w * 512]);
                BAR_VM(2);                    // cur landed; nxt in flight
            } else {
                BAR_VM(0);
            }
            if (kb > q0w + 15) continue;      // fully masked for this wave

            // S^T = K Q^T (scores already in log2 units): rows=keys, col q=lrow
            float4v st[4];
            for (int f = 0; f < 4; f++) {
                float4v z = {};
                const half_t* kr = &Ks[cur][(f * 16 + lrow) * 64];
                half8 k0 = *(const half8*)(kr + cA);
                half8 k1 = *(const half8*)(kr + cB);
                z = __builtin_amdgcn_mfma_f32_16x16x32_f16(k0, qf0, z, 0, 0, 0);
                z = __builtin_amdgcn_mfma_f32_16x16x32_f16(k1, qf1, z, 0, 0, 0);
                st[f] = z;
            }
            if (kb + 63 > q0w) {              // diagonal-crossing tile
                int qabs = q0w + lrow;
                for (int f = 0; f < 4; f++)
                    for (int r = 0; r < 4; r++) {
                        int key = kb + f * 16 + quad * 4 + r;
                        if (key > qabs) st[f][r] = -__builtin_inff();
                    }
            }
            float tm = st[0][0];
            for (int f = 0; f < 4; f++)
                for (int r = 0; r < 4; r++) tm = fmaxf(tm, st[f][r]);
            tm = fmaxf(tm, __shfl_xor(tm, 16));
            tm = fmaxf(tm, __shfl_xor(tm, 32));
            float mn = fmaxf(m, tm);
            float alpha = __builtin_amdgcn_exp2f(m - mn);
            m = mn;
            float rs = 0.f;
            for (int f = 0; f < 4; f++) {
                float p0 = __builtin_amdgcn_exp2f(st[f][0] - mn);
                float p1 = __builtin_amdgcn_exp2f(st[f][1] - mn);
                float p2 = __builtin_amdgcn_exp2f(st[f][2] - mn);
                float p3 = __builtin_amdgcn_exp2f(st[f][3] - mn);
                rs += (p0 + p1) + (p2 + p3);
                uint2 pw;
                pw.x = __builtin_bit_cast(unsigned, __builtin_amdgcn_cvt_pkrtz(p0, p1));
                pw.y = __builtin_bit_cast(unsigned, __builtin_amdgcn_cvt_pkrtz(p2, p3));
                int cc = (2 * f + (quad >> 1)) ^ sw;
                *(uint2*)(PsW + cc * 8 + (quad & 1) * 4) = pw;
            }
            rs += __shfl_xor(rs, 16);
            rs += __shfl_xor(rs, 32);
            l = l * alpha + rs;
            for (int f2 = 0; f2 < 4; f2++)
                for (int r = 0; r < 4; r++) ot[f2][r] *= alpha;

            __asm__ volatile("s_waitcnt lgkmcnt(0)" ::: "memory");  // P writes visible
            half8 p0v = *(const half8*)(PsW + cA);
            half8 p1v = *(const half8*)(PsW + cB);
            for (int f2 = 0; f2 < 4; f2++) {
                const half_t* vr = &Vs[cur][(f2 * 16 + lrow) * 64];
                half8 v0 = *(const half8*)(vr + cA);
                half8 v1 = *(const half8*)(vr + cB);
                ot[f2] = __builtin_amdgcn_mfma_f32_16x16x32_f16(v0, p0v, ot[f2], 0, 0, 0);
                ot[f2] = __builtin_amdgcn_mfma_f32_16x16x32_f16(v1, p1v, ot[f2], 0, 0, 0);
            }
        }

        float inv = 1.0f / l;
        size_t base = ((size_t)(b * 2048) + q0w + lrow) * 1024 + h * 64;
        for (int f2 = 0; f2 < 4; f2++) {
            half4v oh;
            for (int r = 0; r < 4; r++) oh[r] = (half_t)(ot[f2][r] * inv);
            *(half4v*)(Z + base + f2 * 16 + quad * 4) = oh;
        }
    }
}

// ---------------- launch ----------------
extern "C" void kernel_launch(void* const* d_in, const int* in_sizes, int n_in,
                              void* d_out, int out_size, void* d_ws, size_t ws_size,
                              hipStream_t stream)
{
    const float* x     = (const float*)d_in[0];
    // d_in[1] = mask (causal, known analytically) - unused
    const float* W_qkv = (const float*)d_in[2];
    const float* b_qkv = (const float*)d_in[3];
    const float* W_o   = (const float*)d_in[4];
    const float* b_o   = (const float*)d_in[5];
    const float* wq    = (const float*)d_in[6];
    const float* wk    = (const float*)d_in[7];
    float* out = (float*)d_out;

    char* ws = (char*)d_ws;
    half_t* xh   = (half_t*)(ws);                     // 16 MB (reused as zh after attn)
    half_t* Wqt  = (half_t*)(ws + (16ull << 20));     // 6 MB
    half_t* Wot  = (half_t*)(ws + (22ull << 20));     // 2 MB
    half_t* Qh   = (half_t*)(ws + (40ull << 20));     // 16 MB
    half_t* Kh   = (half_t*)(ws + (56ull << 20));     // 16 MB
    half_t* Vt   = (half_t*)(ws + (72ull << 20));     // 16 MB
    half_t* zh   = xh;

    cast_f32_f16<<<8192, 256, 0, stream>>>(x, xh, 8192 * 1024);
    transpose_cast<<<dim3(96, 32), dim3(32, 8), 0, stream>>>(W_qkv, Wqt, 1024, 3072);
    transpose_cast<<<dim3(32, 32), dim3(32, 8), 0, stream>>>(W_o, Wot, 1024, 1024);
    gemm_f16<1><<<dim3(64, 24), 256, 0, stream>>>(xh, Wqt, b_qkv, Vt, 8192, 3072, 1024,
                                                  wq, wk, Qh, Kh);
    attn<<<dim3(64, 8), 512, 0, stream>>>(Qh, Kh, Vt, zh);
    gemm_f16<0><<<dim3(64, 8), 256, 0, stream>>>(zh, Wot, b_o, out, 8192, 1024, 1024,
                                                 nullptr, nullptr, nullptr, nullptr);
}

// Round 10
// 272.598 us; speedup vs baseline: 1.0504x; 1.0504x over previous
//
#include <hip/hip_runtime.h>
#include <cmath>

typedef _Float16 half_t;
typedef _Float16 half8 __attribute__((ext_vector_type(8)));
typedef _Float16 half4v __attribute__((ext_vector_type(4)));
typedef float float4v __attribute__((ext_vector_type(4)));

#define LOG2E 1.44269504088896340736f

#define GLDS16(g, l)                                                                   \
    __builtin_amdgcn_global_load_lds((const __attribute__((address_space(1))) void*)(g), \
                                     (__attribute__((address_space(3))) void*)(l), 16, 0, 0)

// raw barriers: no compiler-inserted vmcnt(0) drain (the __syncthreads trap)
#define BAR_LGKM() __asm__ volatile("s_waitcnt lgkmcnt(0)\n\ts_barrier" ::: "memory")
#define BAR_VM(n)  __asm__ volatile("s_waitcnt vmcnt(" #n ")\n\ts_barrier" ::: "memory")

// ---------------- cast fp32 -> fp16 ----------------
__global__ void cast_f32_f16(const float* __restrict__ in, half_t* __restrict__ out, int n) {
    int i = (blockIdx.x * blockDim.x + threadIdx.x) * 4;
    if (i >= n) return;
    float4 v = *(const float4*)(in + i);
    half4v o;
    o[0] = (half_t)v.x; o[1] = (half_t)v.y; o[2] = (half_t)v.z; o[3] = (half_t)v.w;
    *(half4v*)(out + i) = o;
}

// ---------------- transpose + cast: in fp32 [R][C] -> out fp16 [C][R] ----------------
__global__ void transpose_cast(const float* __restrict__ in, half_t* __restrict__ out, int R, int C) {
    __shared__ float tile[32][33];
    int c0 = blockIdx.x * 32, r0 = blockIdx.y * 32;
    int tx = threadIdx.x, ty = threadIdx.y; // block (32,8)
    for (int p = 0; p < 4; p++) {
        int r = r0 + ty + p * 8;
        tile[ty + p * 8][tx] = in[(size_t)r * C + c0 + tx];
    }
    __syncthreads();
    for (int p = 0; p < 4; p++) {
        int c = c0 + ty + p * 8;
        out[(size_t)c * R + r0 + tx] = (half_t)tile[tx][ty + p * 8];
    }
}

// ---------------- GEMM: C[M][N] = A[M][K] * Bt[N][K]^T + bias ----------------
// 128x128 tile, BK=32, 4 waves; triple-buffered global_load_lds (prefetch
// distance 2, vmcnt(8) mid-loop), raw barriers, bank-swizzled LDS (0 conflicts).
// __launch_bounds__(256,3): target 3 waves/SIMD (VGPR+AGPR budget ~170) — the
// r9 kernel sat at 104+64=168 but allocation granularity dropped it to 2/SIMD.
// MODE 0: fp32 out + bias. MODE 1: QKV epilogue — RMSNorm per head (Q pre-scaled
// by LOG2E) -> Qh/Kh head-major; V stored transposed into Vt[bh][d][s].
template <int MODE>
__global__ __launch_bounds__(256, 3) void gemm_f16(
    const half_t* __restrict__ A,   // [M][K]
    const half_t* __restrict__ Bt,  // [N][K]
    const float* __restrict__ bias, // [N]
    void* __restrict__ Cout,
    int M, int N, int K,
    const float* __restrict__ wq, const float* __restrict__ wk,
    half_t* __restrict__ Qh, half_t* __restrict__ Kh)
{
    __shared__ __align__(16) half_t As[3][128 * 32];
    __shared__ __align__(16) half_t Bs[3][128 * 32];
    int t = threadIdx.x;
    int lane = t & 63, w = t >> 6;
    int m0 = blockIdx.x * 128, n0 = blockIdx.y * 128;
    int wm = (w >> 1) * 64, wn = (w & 1) * 64;
    int lrow = lane & 15, quad = lane >> 4;

    // staging: thread t covers row t>>2, stored pos t&3 -> loads logical chunk lc
    int lc = ((t & 3) - (t >> 3)) & 3;
    const half_t* gA = A  + (size_t)(m0 + (t >> 2)) * K + lc * 8;
    const half_t* gB = Bt + (size_t)(n0 + (t >> 2)) * K + lc * 8;
    half_t* ldsA[3] = { &As[0][w * 512], &As[1][w * 512], &As[2][w * 512] };
    half_t* ldsB[3] = { &Bs[0][w * 512], &Bs[1][w * 512], &Bs[2][w * 512] };

    // fragment reads: logical chunk = quad, stored pos uniform across frags
    int posq = (quad + (lrow >> 1)) & 3;

    float4v acc[4][4] = {};

    // preload tiles 0,1 -> buf 0,1
    GLDS16(gA,                       ldsA[0]);
    GLDS16(gA + (size_t)64 * K,      ldsA[0] + 2048);
    GLDS16(gB,                       ldsB[0]);
    GLDS16(gB + (size_t)64 * K,      ldsB[0] + 2048);
    GLDS16(gA + 32,                  ldsA[1]);
    GLDS16(gA + (size_t)64 * K + 32, ldsA[1] + 2048);
    GLDS16(gB + 32,                  ldsB[1]);
    GLDS16(gB + (size_t)64 * K + 32, ldsB[1] + 2048);

    int nk = K >> 5;
    for (int ki = 0; ki < nk; ki++) {
        int cur = ki % 3, pre = (ki + 2) % 3;
        BAR_LGKM();                         // readers of buf pre (iter ki-1) done
        if (ki + 2 < nk) {
            int kp = (ki + 2) << 5;
            GLDS16(gA + kp,                  ldsA[pre]);
            GLDS16(gA + (size_t)64 * K + kp, ldsA[pre] + 2048);
            GLDS16(gB + kp,                  ldsB[pre]);
            GLDS16(gB + (size_t)64 * K + kp, ldsB[pre] + 2048);
            BAR_VM(8);                      // cur landed; ki+1, ki+2 in flight
        } else if (ki + 1 < nk) {
            BAR_VM(4);
        } else {
            BAR_VM(0);
        }
        half8 af[4], bf[4];
        for (int i = 0; i < 4; i++) af[i] = *(const half8*)(&As[cur][(wm + i * 16 + lrow) * 32 + posq * 8]);
        for (int i = 0; i < 4; i++) bf[i] = *(const half8*)(&Bs[cur][(wn + i * 16 + lrow) * 32 + posq * 8]);
        for (int mi = 0; mi < 4; mi++)
            for (int ni = 0; ni < 4; ni++)
                acc[mi][ni] = __builtin_amdgcn_mfma_f32_16x16x32_f16(af[mi], bf[ni], acc[mi][ni], 0, 0, 0);
    }

    if (MODE == 0) {
        float* out = (float*)Cout;
        for (int mi = 0; mi < 4; mi++)
            for (int ni = 0; ni < 4; ni++)
                for (int r = 0; r < 4; r++) {
                    int gr = m0 + wm + mi * 16 + quad * 4 + r;
                    int gc = n0 + wn + ni * 16 + lrow;
                    out[(size_t)gr * N + gc] = acc[mi][ni][r] + bias[gc];
                }
    } else {
        int nglob = n0 + wn;            // 64-aligned; one head per wave
        if (nglob < 2048) {
            int isK = nglob >> 10;
            int h = (nglob >> 6) & 15;
            const float* wv = isK ? wk : wq;
            half_t* dst = isK ? Kh : Qh;
            float post = isK ? 1.0f : LOG2E;   // pre-scale Q so attn works in log2 domain
            for (int mi = 0; mi < 4; mi++)
                for (int r = 0; r < 4; r++) {
                    int gr = m0 + wm + mi * 16 + quad * 4 + r;
                    float v[4]; float ss = 0.f;
                    for (int ni = 0; ni < 4; ni++) {
                        v[ni] = acc[mi][ni][r] + bias[nglob + ni * 16 + lrow];
                        ss += v[ni] * v[ni];
                    }
                    ss += __shfl_xor(ss, 1);
                    ss += __shfl_xor(ss, 2);
                    ss += __shfl_xor(ss, 4);
                    ss += __shfl_xor(ss, 8);
                    float rr = rsqrtf(ss * (1.0f / 64.0f) + 1e-6f) * post;
                    int bb = gr >> 11, s = gr & 2047;
                    size_t rowbase = ((size_t)((bb * 16 + h) * 2048 + s)) * 64;
                    for (int ni = 0; ni < 4; ni++) {
                        int d = ni * 16 + lrow;
                        dst[rowbase + d] = (half_t)(v[ni] * rr * wv[d]);
                    }
                }
        } else {
            // V part: store transposed into Vt[bh][d][s] (4 consecutive s per lane)
            half_t* Vt = (half_t*)Cout;
            for (int mi = 0; mi < 4; mi++) {
                int gr = m0 + wm + mi * 16 + quad * 4;   // s-base, 4-aligned
                int bb = gr >> 11, s = gr & 2047;
                for (int ni = 0; ni < 4; ni++) {
                    int dg = nglob + ni * 16 + lrow - 2048;   // 0..1023
                    float bv = bias[nglob + ni * 16 + lrow];
                    half4v oh;
                    for (int r = 0; r < 4; r++) oh[r] = (half_t)(acc[mi][ni][r] + bv);
                    *(half4v*)(Vt + ((size_t)((bb * 16 + (dg >> 6)) * 64 + (dg & 63))) * 2048 + s) = oh;
                }
            }
        }
    }
}

// ---------------- Flash attention, causal, no scale (Q pre-scaled by LOG2E) --
// 8 waves / 128 q-rows, paired q-tiles (i,15-i), XOR-swizzled LDS,
// grid (bh, pair) for XCD L2 sharing, dbuf K/V with RAW barriers (vmcnt(2)).
__global__ __launch_bounds__(512, 4) void attn(
    const half_t* __restrict__ Qh, const half_t* __restrict__ Kh, const half_t* __restrict__ Vt,
    half_t* __restrict__ Z)
{
    __shared__ __align__(16) half_t Ks[2][64 * 64];   // [buf][key][d], chunk-swizzled
    __shared__ __align__(16) half_t Vs[2][64 * 64];   // [buf][d][key], chunk-swizzled
    __shared__ __align__(16) half_t Ps[8 * 16 * 64];  // per-wave [q][key], chunk-swizzled

    int bh = blockIdx.x;
    int b = bh >> 4, h = bh & 15;
    int t = threadIdx.x, lane = t & 63, w = t >> 6;
    int lrow = lane & 15, quad = lane >> 4;

    int sr = w * 8 + (lane >> 3);
    int scc = (lane & 7) ^ ((lane >> 3) & 7);
    const half_t* gK0 = Kh + ((size_t)bh * 2048 + sr) * 64 + scc * 8;
    const half_t* gV0 = Vt + ((size_t)bh * 64 + sr) * 2048 + scc * 8;

    int sw = lrow & 7;
    int cA = (quad ^ sw) * 8;
    int cB = ((quad + 4) ^ sw) * 8;
    half_t* PsW = Ps + w * 1024 + lrow * 64;

    for (int pass = 0; pass < 2; pass++) {
        int qt = pass ? (15 - (int)blockIdx.y) : (int)blockIdx.y;
        int q0w = qt * 128 + w * 16;

        const half_t* Qbase = Qh + ((size_t)bh * 2048 + q0w + lrow) * 64;
        half8 qf0 = *(const half8*)(Qbase + quad * 8);
        half8 qf1 = *(const half8*)(Qbase + 32 + quad * 8);

        float4v ot[4] = {};
        float m = -__builtin_inff(), l = 0.f;

        int nt = 2 * qt + 2;
        __syncthreads();                      // full drain at pass boundary
        GLDS16(gK0, &Ks[0][w * 512]);
        GLDS16(gV0, &Vs[0][w * 512]);

        for (int kt = 0; kt < nt; kt++) {
            int cur = kt & 1, nxt = cur ^ 1;
            int kb = kt * 64;
            BAR_LGKM();                       // prev readers of buf nxt done
            if (kt + 1 < nt) {
                GLDS16(gK0 + (size_t)(kb + 64) * 64, &Ks[nxt][w * 512]);
                GLDS16(gV0 + kb + 64,                &Vs[nxt][w * 512]);
                BAR_VM(2);                    // cur landed; nxt in flight
            } else {
                BAR_VM(0);
            }
            if (kb > q0w + 15) continue;      // fully masked for this wave

            // S^T = K Q^T (scores already in log2 units): rows=keys, col q=lrow
            float4v st[4];
            for (int f = 0; f < 4; f++) {
                float4v z = {};
                const half_t* kr = &Ks[cur][(f * 16 + lrow) * 64];
                half8 k0 = *(const half8*)(kr + cA);
                half8 k1 = *(const half8*)(kr + cB);
                z = __builtin_amdgcn_mfma_f32_16x16x32_f16(k0, qf0, z, 0, 0, 0);
                z = __builtin_amdgcn_mfma_f32_16x16x32_f16(k1, qf1, z, 0, 0, 0);
                st[f] = z;
            }
            if (kb + 63 > q0w) {              // diagonal-crossing tile
                int qabs = q0w + lrow;
                for (int f = 0; f < 4; f++)
                    for (int r = 0; r < 4; r++) {
                        int key = kb + f * 16 + quad * 4 + r;
                        if (key > qabs) st[f][r] = -__builtin_inff();
                    }
            }
            float tm = st[0][0];
            for (int f = 0; f < 4; f++)
                for (int r = 0; r < 4; r++) tm = fmaxf(tm, st[f][r]);
            tm = fmaxf(tm, __shfl_xor(tm, 16));
            tm = fmaxf(tm, __shfl_xor(tm, 32));
            float mn = fmaxf(m, tm);
            float alpha = __builtin_amdgcn_exp2f(m - mn);
            m = mn;
            float rs = 0.f;
            for (int f = 0; f < 4; f++) {
                float p0 = __builtin_amdgcn_exp2f(st[f][0] - mn);
                float p1 = __builtin_amdgcn_exp2f(st[f][1] - mn);
                float p2 = __builtin_amdgcn_exp2f(st[f][2] - mn);
                float p3 = __builtin_amdgcn_exp2f(st[f][3] - mn);
                rs += (p0 + p1) + (p2 + p3);
                uint2 pw;
                pw.x = __builtin_bit_cast(unsigned, __builtin_amdgcn_cvt_pkrtz(p0, p1));
                pw.y = __builtin_bit_cast(unsigned, __builtin_amdgcn_cvt_pkrtz(p2, p3));
                int cc = (2 * f + (quad >> 1)) ^ sw;
                *(uint2*)(PsW + cc * 8 + (quad & 1) * 4) = pw;
            }
            rs += __shfl_xor(rs, 16);
            rs += __shfl_xor(rs, 32);
            l = l * alpha + rs;
            for (int f2 = 0; f2 < 4; f2++)
                for (int r = 0; r < 4; r++) ot[f2][r] *= alpha;

            __asm__ volatile("s_waitcnt lgkmcnt(0)" ::: "memory");  // P writes visible
            half8 p0v = *(const half8*)(PsW + cA);
            half8 p1v = *(const half8*)(PsW + cB);
            for (int f2 = 0; f2 < 4; f2++) {
                const half_t* vr = &Vs[cur][(f2 * 16 + lrow) * 64];
                half8 v0 = *(const half8*)(vr + cA);
                half8 v1 = *(const half8*)(vr + cB);
                ot[f2] = __builtin_amdgcn_mfma_f32_16x16x32_f16(v0, p0v, ot[f2], 0, 0, 0);
                ot[f2] = __builtin_amdgcn_mfma_f32_16x16x32_f16(v1, p1v, ot[f2], 0, 0, 0);
            }
        }

        float inv = 1.0f / l;
        size_t base = ((size_t)(b * 2048) + q0w + lrow) * 1024 + h * 64;
        for (int f2 = 0; f2 < 4; f2++) {
            half4v oh;
            for (int r = 0; r < 4; r++) oh[r] = (half_t)(ot[f2][r] * inv);
            *(half4v*)(Z + base + f2 * 16 + quad * 4) = oh;
        }
    }
}

// ---------------- launch ----------------
extern "C" void kernel_launch(void* const* d_in, const int* in_sizes, int n_in,
                              void* d_out, int out_size, void* d_ws, size_t ws_size,
                              hipStream_t stream)
{
    const float* x     = (const float*)d_in[0];
    // d_in[1] = mask (causal, known analytically) - unused
    const float* W_qkv = (const float*)d_in[2];
    const float* b_qkv = (const float*)d_in[3];
    const float* W_o   = (const float*)d_in[4];
    const float* b_o   = (const float*)d_in[5];
    const float* wq    = (const float*)d_in[6];
    const float* wk    = (const float*)d_in[7];
    float* out = (float*)d_out;

    char* ws = (char*)d_ws;
    half_t* xh   = (half_t*)(ws);                     // 16 MB (reused as zh after attn)
    half_t* Wqt  = (half_t*)(ws + (16ull << 20));     // 6 MB
    half_t* Wot  = (half_t*)(ws + (22ull << 20));     // 2 MB
    half_t* Qh   = (half_t*)(ws + (40ull << 20));     // 16 MB
    half_t* Kh   = (half_t*)(ws + (56ull << 20));     // 16 MB
    half_t* Vt   = (half_t*)(ws + (72ull << 20));     // 16 MB
    half_t* zh   = xh;

    cast_f32_f16<<<8192, 256, 0, stream>>>(x, xh, 8192 * 1024);
    transpose_cast<<<dim3(96, 32), dim3(32, 8), 0, stream>>>(W_qkv, Wqt, 1024, 3072);
    transpose_cast<<<dim3(32, 32), dim3(32, 8), 0, stream>>>(W_o, Wot, 1024, 1024);
    gemm_f16<1><<<dim3(64, 24), 256, 0, stream>>>(xh, Wqt, b_qkv, Vt, 8192, 3072, 1024,
                                                  wq, wk, Qh, Kh);
    attn<<<dim3(64, 8), 512, 0, stream>>>(Qh, Kh, Vt, zh);
    gemm_f16<0><<<dim3(64, 8), 256, 0, stream>>>(zh, Wot, b_o, out, 8192, 1024, 1024,
                                                 nullptr, nullptr, nullptr, nullptr);
}

// Round 12
// 272.471 us; speedup vs baseline: 1.0509x; 1.0005x over previous
//
#include <hip/hip_runtime.h>
#include <cmath>

typedef _Float16 half_t;
typedef _Float16 half8 __attribute__((ext_vector_type(8)));
typedef _Float16 half4v __attribute__((ext_vector_type(4)));
typedef float float4v __attribute__((ext_vector_type(4)));

#define LOG2E 1.44269504088896340736f

#define GLDS16(g, l)                                                                   \
    __builtin_amdgcn_global_load_lds((const __attribute__((address_space(1))) void*)(g), \
                                     (__attribute__((address_space(3))) void*)(l), 16, 0, 0)

// raw barriers: no compiler-inserted vmcnt(0) drain (the __syncthreads trap)
#define BAR_LGKM() __asm__ volatile("s_waitcnt lgkmcnt(0)\n\ts_barrier" ::: "memory")
#define BAR_VM(n)  __asm__ volatile("s_waitcnt vmcnt(" #n ")\n\ts_barrier" ::: "memory")

// ---------------- cast fp32 -> fp16 ----------------
__global__ void cast_f32_f16(const float* __restrict__ in, half_t* __restrict__ out, int n) {
    int i = (blockIdx.x * blockDim.x + threadIdx.x) * 4;
    if (i >= n) return;
    float4 v = *(const float4*)(in + i);
    half4v o;
    o[0] = (half_t)v.x; o[1] = (half_t)v.y; o[2] = (half_t)v.z; o[3] = (half_t)v.w;
    *(half4v*)(out + i) = o;
}

// ---------------- transpose + cast: in fp32 [R][C] -> out fp16 [C][R] ----------------
__global__ void transpose_cast(const float* __restrict__ in, half_t* __restrict__ out, int R, int C) {
    __shared__ float tile[32][33];
    int c0 = blockIdx.x * 32, r0 = blockIdx.y * 32;
    int tx = threadIdx.x, ty = threadIdx.y; // block (32,8)
    for (int p = 0; p < 4; p++) {
        int r = r0 + ty + p * 8;
        tile[ty + p * 8][tx] = in[(size_t)r * C + c0 + tx];
    }
    __syncthreads();
    for (int p = 0; p < 4; p++) {
        int c = c0 + ty + p * 8;
        out[(size_t)c * R + r0 + tx] = (half_t)tile[tx][ty + p * 8];
    }
}

// ---------------- GEMM: C[M][N] = A[M][K] * Bt[N][K]^T + bias ----------------
// (r10 config: triple-buffered GLDS, raw barriers, bank-swizzle, 3 waves/SIMD)
template <int MODE>
__global__ __launch_bounds__(256, 3) void gemm_f16(
    const half_t* __restrict__ A,   // [M][K]
    const half_t* __restrict__ Bt,  // [N][K]
    const float* __restrict__ bias, // [N]
    void* __restrict__ Cout,
    int M, int N, int K,
    const float* __restrict__ wq, const float* __restrict__ wk,
    half_t* __restrict__ Qh, half_t* __restrict__ Kh)
{
    __shared__ __align__(16) half_t As[3][128 * 32];
    __shared__ __align__(16) half_t Bs[3][128 * 32];
    int t = threadIdx.x;
    int lane = t & 63, w = t >> 6;
    int m0 = blockIdx.x * 128, n0 = blockIdx.y * 128;
    int wm = (w >> 1) * 64, wn = (w & 1) * 64;
    int lrow = lane & 15, quad = lane >> 4;

    int lc = ((t & 3) - (t >> 3)) & 3;
    const half_t* gA = A  + (size_t)(m0 + (t >> 2)) * K + lc * 8;
    const half_t* gB = Bt + (size_t)(n0 + (t >> 2)) * K + lc * 8;
    half_t* ldsA[3] = { &As[0][w * 512], &As[1][w * 512], &As[2][w * 512] };
    half_t* ldsB[3] = { &Bs[0][w * 512], &Bs[1][w * 512], &Bs[2][w * 512] };

    int posq = (quad + (lrow >> 1)) & 3;

    float4v acc[4][4] = {};

    GLDS16(gA,                       ldsA[0]);
    GLDS16(gA + (size_t)64 * K,      ldsA[0] + 2048);
    GLDS16(gB,                       ldsB[0]);
    GLDS16(gB + (size_t)64 * K,      ldsB[0] + 2048);
    GLDS16(gA + 32,                  ldsA[1]);
    GLDS16(gA + (size_t)64 * K + 32, ldsA[1] + 2048);
    GLDS16(gB + 32,                  ldsB[1]);
    GLDS16(gB + (size_t)64 * K + 32, ldsB[1] + 2048);

    int nk = K >> 5;
    for (int ki = 0; ki < nk; ki++) {
        int cur = ki % 3, pre = (ki + 2) % 3;
        BAR_LGKM();
        if (ki + 2 < nk) {
            int kp = (ki + 2) << 5;
            GLDS16(gA + kp,                  ldsA[pre]);
            GLDS16(gA + (size_t)64 * K + kp, ldsA[pre] + 2048);
            GLDS16(gB + kp,                  ldsB[pre]);
            GLDS16(gB + (size_t)64 * K + kp, ldsB[pre] + 2048);
            BAR_VM(8);
        } else if (ki + 1 < nk) {
            BAR_VM(4);
        } else {
            BAR_VM(0);
        }
        half8 af[4], bf[4];
        for (int i = 0; i < 4; i++) af[i] = *(const half8*)(&As[cur][(wm + i * 16 + lrow) * 32 + posq * 8]);
        for (int i = 0; i < 4; i++) bf[i] = *(const half8*)(&Bs[cur][(wn + i * 16 + lrow) * 32 + posq * 8]);
        for (int mi = 0; mi < 4; mi++)
            for (int ni = 0; ni < 4; ni++)
                acc[mi][ni] = __builtin_amdgcn_mfma_f32_16x16x32_f16(af[mi], bf[ni], acc[mi][ni], 0, 0, 0);
    }

    if (MODE == 0) {
        float* out = (float*)Cout;
        for (int mi = 0; mi < 4; mi++)
            for (int ni = 0; ni < 4; ni++)
                for (int r = 0; r < 4; r++) {
                    int gr = m0 + wm + mi * 16 + quad * 4 + r;
                    int gc = n0 + wn + ni * 16 + lrow;
                    out[(size_t)gr * N + gc] = acc[mi][ni][r] + bias[gc];
                }
    } else {
        int nglob = n0 + wn;            // 64-aligned; one head per wave
        if (nglob < 2048) {
            int isK = nglob >> 10;
            int h = (nglob >> 6) & 15;
            const float* wv = isK ? wk : wq;
            half_t* dst = isK ? Kh : Qh;
            float post = isK ? 1.0f : LOG2E;   // pre-scale Q so attn works in log2 domain
            for (int mi = 0; mi < 4; mi++)
                for (int r = 0; r < 4; r++) {
                    int gr = m0 + wm + mi * 16 + quad * 4 + r;
                    float v[4]; float ss = 0.f;
                    for (int ni = 0; ni < 4; ni++) {
                        v[ni] = acc[mi][ni][r] + bias[nglob + ni * 16 + lrow];
                        ss += v[ni] * v[ni];
                    }
                    ss += __shfl_xor(ss, 1);
                    ss += __shfl_xor(ss, 2);
                    ss += __shfl_xor(ss, 4);
                    ss += __shfl_xor(ss, 8);
                    float rr = rsqrtf(ss * (1.0f / 64.0f) + 1e-6f) * post;
                    int bb = gr >> 11, s = gr & 2047;
                    size_t rowbase = ((size_t)((bb * 16 + h) * 2048 + s)) * 64;
                    for (int ni = 0; ni < 4; ni++) {
                        int d = ni * 16 + lrow;
                        dst[rowbase + d] = (half_t)(v[ni] * rr * wv[d]);
                    }
                }
        } else {
            // V part: store transposed into Vt[bh][d][s]
            half_t* Vt = (half_t*)Cout;
            for (int mi = 0; mi < 4; mi++) {
                int gr = m0 + wm + mi * 16 + quad * 4;   // s-base, 4-aligned
                int bb = gr >> 11, s = gr & 2047;
                for (int ni = 0; ni < 4; ni++) {
                    int dg = nglob + ni * 16 + lrow - 2048;   // 0..1023
                    float bv = bias[nglob + ni * 16 + lrow];
                    half4v oh;
                    for (int r = 0; r < 4; r++) oh[r] = (half_t)(acc[mi][ni][r] + bv);
                    *(half4v*)(Vt + ((size_t)((bb * 16 + (dg >> 6)) * 64 + (dg & 63))) * 2048 + s) = oh;
                }
            }
        }
    }
}

// ---------------- Flash attention, causal, no scale (Q pre-scaled by LOG2E) --
// 8 waves / 128 q-rows, paired q-tiles (i,15-i), grid (bh, pair) for XCD L2.
// 128-KEY iterations: 8 QK MFMA + ONE softmax round + 16 PV MFMA in two
// P-half-rounds. K/V store position = chunk ^ (row & 7); ALL reads use
// sw = lrow & 7 for the XOR (r11 bug: V reads XORed 4 bits of lrow).
__global__ __launch_bounds__(512, 4) void attn(
    const half_t* __restrict__ Qh, const half_t* __restrict__ Kh, const half_t* __restrict__ Vt,
    half_t* __restrict__ Z)
{
    __shared__ __align__(16) half_t Ks[2][128 * 64];  // [buf][key][d], pos = chunk ^ (key&7)
    __shared__ __align__(16) half_t Vs[2][64 * 128];  // [buf][d][key], pos = chunk ^ (d&7)
    __shared__ __align__(16) half_t Ps[8][16 * 64];   // per-wave [q][key-half]

    int bh = blockIdx.x;
    int b = bh >> 4, h = bh & 15;
    int t = threadIdx.x, lane = t & 63, w = t >> 6;
    int lrow = lane & 15, quad = lane >> 4;

    // K staging: GLDS j covers rows w*16 + j*8 + (lane>>3), stored chunk lane&7
    int scc = (lane & 7) ^ ((lane >> 3) & 7);
    const half_t* gK0 = Kh + ((size_t)bh * 2048 + w * 16 + (lane >> 3)) * 64 + scc * 8;
    // V staging: GLDS j covers d-row w*8 + j*4 + (lane>>4), stored chunk lane&15
    int vr0 = w * 8 + (lane >> 4);
    int vc0 = (lane & 15) ^ (lane >> 4);
    int vc1 = (lane & 15) ^ ((lane >> 4) + 4);
    const half_t* gV0 = Vt + ((size_t)bh * 64 + vr0) * 2048 + vc0 * 8;
    const half_t* gV1 = Vt + ((size_t)bh * 64 + vr0 + 4) * 2048 + vc1 * 8;
    half_t* ldsK[2] = { &Ks[0][w * 1024], &Ks[1][w * 1024] };
    half_t* ldsV[2] = { &Vs[0][w * 1024], &Vs[1][w * 1024] };

    int sw = lrow & 7;
    int cA = (quad ^ sw) * 8;          // Ks d-chunk quad, Ps key-chunk quad
    int cB = ((quad + 4) ^ sw) * 8;    // Ks d-chunk quad+4, Ps key-chunk quad+4
    half_t* PsW = &Ps[w][lrow * 64];

    for (int pass = 0; pass < 2; pass++) {
        int qt = pass ? (15 - (int)blockIdx.y) : (int)blockIdx.y;
        int q0w = qt * 128 + w * 16;

        const half_t* Qbase = Qh + ((size_t)bh * 2048 + q0w + lrow) * 64;
        half8 qf0 = *(const half8*)(Qbase + quad * 8);
        half8 qf1 = *(const half8*)(Qbase + 32 + quad * 8);

        float4v ot[4] = {};
        float m = -__builtin_inff(), l = 0.f;

        int nt = qt + 1;                      // 128-key tiles
        __syncthreads();                      // full drain at pass boundary
        GLDS16(gK0,       ldsK[0]);
        GLDS16(gK0 + 512, ldsK[0] + 512);
        GLDS16(gV0,       ldsV[0]);
        GLDS16(gV1,       ldsV[0] + 512);

        for (int kt = 0; kt < nt; kt++) {
            int cur = kt & 1, nxt = cur ^ 1;
            int kb = kt * 128;
            BAR_LGKM();                       // prev readers of buf nxt done
            if (kt + 1 < nt) {
                size_t ko = (size_t)(kb + 128);
                GLDS16(gK0 + ko * 64,       ldsK[nxt]);
                GLDS16(gK0 + ko * 64 + 512, ldsK[nxt] + 512);
                GLDS16(gV0 + ko,            ldsV[nxt]);
                GLDS16(gV1 + ko,            ldsV[nxt] + 512);
                BAR_VM(4);                    // cur landed; nxt in flight
            } else {
                BAR_VM(0);
            }

            // S^T = K Q^T : st[f] keys = kb + 16f + quad*4 + r, col q = lrow
            float4v st[8];
            for (int f = 0; f < 8; f++) {
                float4v z = {};
                const half_t* kr = &Ks[cur][(f * 16 + lrow) * 64];
                half8 k0 = *(const half8*)(kr + cA);
                half8 k1 = *(const half8*)(kr + cB);
                z = __builtin_amdgcn_mfma_f32_16x16x32_f16(k0, qf0, z, 0, 0, 0);
                z = __builtin_amdgcn_mfma_f32_16x16x32_f16(k1, qf1, z, 0, 0, 0);
                st[f] = z;
            }
            if (kb + 127 > q0w) {             // tile crosses diagonal for this strip
                int qabs = q0w + lrow;
                for (int f = 0; f < 8; f++)
                    for (int r = 0; r < 4; r++) {
                        int key = kb + f * 16 + quad * 4 + r;
                        if (key > qabs) st[f][r] = -__builtin_inff();
                    }
            }
            // ONE softmax round over 32 lane-values + 2 cross-quad shfls
            float tm = st[0][0];
            for (int f = 0; f < 8; f++)
                for (int r = 0; r < 4; r++) tm = fmaxf(tm, st[f][r]);
            tm = fmaxf(tm, __shfl_xor(tm, 16));
            tm = fmaxf(tm, __shfl_xor(tm, 32));
            float mn = fmaxf(m, tm);
            float alpha = __builtin_amdgcn_exp2f(m - mn);
            m = mn;
            float rs = 0.f;
            uint2 pw1[4];                     // packed P, key-half 1 (kept in regs)
            for (int f = 0; f < 8; f++) {
                float p0 = __builtin_amdgcn_exp2f(st[f][0] - mn);
                float p1 = __builtin_amdgcn_exp2f(st[f][1] - mn);
                float p2 = __builtin_amdgcn_exp2f(st[f][2] - mn);
                float p3 = __builtin_amdgcn_exp2f(st[f][3] - mn);
                rs += (p0 + p1) + (p2 + p3);
                uint2 pw;
                pw.x = __builtin_bit_cast(unsigned, __builtin_amdgcn_cvt_pkrtz(p0, p1));
                pw.y = __builtin_bit_cast(unsigned, __builtin_amdgcn_cvt_pkrtz(p2, p3));
                if (f < 4) {                  // half 0 -> LDS now
                    int cc = (2 * f + (quad >> 1)) ^ sw;
                    *(uint2*)(PsW + cc * 8 + (quad & 1) * 4) = pw;
                } else {
                    pw1[f - 4] = pw;
                }
            }
            rs += __shfl_xor(rs, 16);
            rs += __shfl_xor(rs, 32);
            l = l * alpha + rs;
            for (int f2 = 0; f2 < 4; f2++)
                for (int r = 0; r < 4; r++) ot[f2][r] *= alpha;

            // PV half 0 (keys kb..kb+63)
            __asm__ volatile("s_waitcnt lgkmcnt(0)" ::: "memory");
            half8 p0v = *(const half8*)(PsW + cA);
            half8 p1v = *(const half8*)(PsW + cB);
            for (int f2 = 0; f2 < 4; f2++) {
                int row = f2 * 16 + lrow;
                half8 v0 = *(const half8*)(&Vs[cur][row * 128 + ((quad ^ sw)) * 8]);
                half8 v1 = *(const half8*)(&Vs[cur][row * 128 + (((4 + quad) ^ sw)) * 8]);
                ot[f2] = __builtin_amdgcn_mfma_f32_16x16x32_f16(v0, p0v, ot[f2], 0, 0, 0);
                ot[f2] = __builtin_amdgcn_mfma_f32_16x16x32_f16(v1, p1v, ot[f2], 0, 0, 0);
            }
            // PV half 1 (keys kb+64..kb+127): overwrite per-wave Ps (DS in-order)
            for (int f = 0; f < 4; f++) {
                int cc = (2 * f + (quad >> 1)) ^ sw;
                *(uint2*)(PsW + cc * 8 + (quad & 1) * 4) = pw1[f];
            }
            __asm__ volatile("s_waitcnt lgkmcnt(0)" ::: "memory");
            half8 p2v = *(const half8*)(PsW + cA);
            half8 p3v = *(const half8*)(PsW + cB);
            for (int f2 = 0; f2 < 4; f2++) {
                int row = f2 * 16 + lrow;
                half8 v2 = *(const half8*)(&Vs[cur][row * 128 + (((8 + quad) ^ sw)) * 8]);
                half8 v3 = *(const half8*)(&Vs[cur][row * 128 + (((12 + quad) ^ sw)) * 8]);
                ot[f2] = __builtin_amdgcn_mfma_f32_16x16x32_f16(v2, p2v, ot[f2], 0, 0, 0);
                ot[f2] = __builtin_amdgcn_mfma_f32_16x16x32_f16(v3, p3v, ot[f2], 0, 0, 0);
            }
        }

        float inv = 1.0f / l;
        size_t base = ((size_t)(b * 2048) + q0w + lrow) * 1024 + h * 64;
        for (int f2 = 0; f2 < 4; f2++) {
            half4v oh;
            for (int r = 0; r < 4; r++) oh[r] = (half_t)(ot[f2][r] * inv);
            *(half4v*)(Z + base + f2 * 16 + quad * 4) = oh;
        }
    }
}

// ---------------- launch ----------------
extern "C" void kernel_launch(void* const* d_in, const int* in_sizes, int n_in,
                              void* d_out, int out_size, void* d_ws, size_t ws_size,
                              hipStream_t stream)
{
    const float* x     = (const float*)d_in[0];
    // d_in[1] = mask (causal, known analytically) - unused
    const float* W_qkv = (const float*)d_in[2];
    const float* b_qkv = (const float*)d_in[3];
    const float* W_o   = (const float*)d_in[4];
    const float* b_o   = (const float*)d_in[5];
    const float* wq    = (const float*)d_in[6];
    const float* wk    = (const float*)d_in[7];
    float* out = (float*)d_out;

    char* ws = (char*)d_ws;
    half_t* xh   = (half_t*)(ws);                     // 16 MB (reused as zh after attn)
    half_t* Wqt  = (half_t*)(ws + (16ull << 20));     // 6 MB
    half_t* Wot  = (half_t*)(ws + (22ull << 20));     // 2 MB
    half_t* Qh   = (half_t*)(ws + (40ull << 20));     // 16 MB
    half_t* Kh   = (half_t*)(ws + (56ull << 20));     // 16 MB
    half_t* Vt   = (half_t*)(ws + (72ull << 20));     // 16 MB
    half_t* zh   = xh;

    cast_f32_f16<<<8192, 256, 0, stream>>>(x, xh, 8192 * 1024);
    transpose_cast<<<dim3(96, 32), dim3(32, 8), 0, stream>>>(W_qkv, Wqt, 1024, 3072);
    transpose_cast<<<dim3(32, 32), dim3(32, 8), 0, stream>>>(W_o, Wot, 1024, 1024);
    gemm_f16<1><<<dim3(64, 24), 256, 0, stream>>>(xh, Wqt, b_qkv, Vt, 8192, 3072, 1024,
                                                  wq, wk, Qh, Kh);
    attn<<<dim3(64, 8), 512, 0, stream>>>(Qh, Kh, Vt, zh);
    gemm_f16<0><<<dim3(64, 8), 256, 0, stream>>>(zh, Wot, b_o, out, 8192, 1024, 1024,
                                                 nullptr, nullptr, nullptr, nullptr);
}